// Round 11
// baseline (2141.539 us; speedup 1.0000x reference)
//
#include <hip/hip_runtime.h>
#include <math.h>

// B=512, D_MODEL=1024, D_INNER=2048, DT_RANK=64, D_STATE=64, NBC=192,
// C_OUT=64, PRED_LEN=96.
// R20: R14 base (plain streams, 96KB wxpin pin) with BARRIER ELIMINATION via
// per-wave redundant compute + per-wave LDS slots (adds ZERO global accesses
// -> immune to the L2-thrash failure mode of R12/13/15/17/18):
//  - bc butterfly computed redundantly by every wave (xor-butterfly is
//    bit-identical across lanes); xdh2q packed into per-wave slot
//    xdh2qW[wid] by lanes 0-31. B3 deleted.
//  - pred reduce computed redundantly by every wave into predH2W[wid];
//    wave 0 writes dout. B6 deleted.
// 6 barriers/step -> 4; the two narrow phases (160 / 128 threads) and their
// idle windows disappear. Same-wave LDS write->read ordered by explicit
// s_waitcnt lgkmcnt(0). Accumulation order identical -> bit-identical.

typedef __fp16 half2_t __attribute__((ext_vector_type(2)));
typedef unsigned int uint32;
union HU { uint32 u; half2_t h; };

__device__ __forceinline__ float sigf(float v){
  return __builtin_amdgcn_rcpf(1.f + __expf(-v));
}
__device__ __forceinline__ uint32 pk2(float a, float b){
  HU x; x.h = __builtin_amdgcn_cvt_pkrtz(a, b); return x.u;
}
__device__ __forceinline__ float dot2(uint32 a, uint32 b, float c){
  HU ua, ub; ua.u = a; ub.u = b;
  return __builtin_amdgcn_fdot2(ua.h, ub.h, c, false);
}
__device__ __forceinline__ void ldsfence(){
  asm volatile("s_waitcnt lgkmcnt(0)" ::: "memory");
}

// ---------------- setup kernels ----------------

__global__ __launch_bounds__(256) void k_ctx(
    const float* __restrict__ ctxin, const float* __restrict__ w_in,
    const float* __restrict__ b_in, float* __restrict__ ctx_xz){
  int tid = threadIdx.x;
  int j = blockIdx.x*256 + tid;
  int b0 = blockIdx.y*16;
  const float* cp = ctxin + (size_t)b0*1024;
  float acc[16];
#pragma unroll
  for (int r=0;r<16;r++) acc[r]=0.f;
  for (int k=0;k<1024;k+=4){
    float w0 = w_in[(size_t)(k+0)*4096 + j];
    float w1 = w_in[(size_t)(k+1)*4096 + j];
    float w2 = w_in[(size_t)(k+2)*4096 + j];
    float w3 = w_in[(size_t)(k+3)*4096 + j];
#pragma unroll
    for (int r=0;r<16;r++){
      acc[r] += cp[r*1024+k]*w0 + cp[r*1024+k+1]*w1
              + cp[r*1024+k+2]*w2 + cp[r*1024+k+3]*w3;
    }
  }
  float bj = b_in[j];
#pragma unroll
  for (int r=0;r<16;r++) ctx_xz[(size_t)(b0+r)*4096 + j] = acc[r] + bj;
}

// W_op[c][o] = sum_k w_out[c][k]*w_proj[k][o]; b_op = b_out@w_proj + b_proj
__global__ __launch_bounds__(256) void k_wop(
    const float* __restrict__ w_out, const float* __restrict__ w_proj,
    const float* __restrict__ b_out, const float* __restrict__ b_proj,
    float* __restrict__ W_op, float* __restrict__ b_op){
  int g = blockIdx.x, tid = threadIdx.x;
  if (g == 512){
    if (tid < 64){
      float s = b_proj[tid];
      for (int k=0;k<1024;k++) s += b_out[k]*w_proj[k*64+tid];
      b_op[tid] = s;
    }
    return;
  }
  int idx = g*256 + tid;
  int c = idx>>6, o = idx&63;
  float s = 0.f;
  const float* wr = w_out + (size_t)c*1024;
  for (int k=0;k<1024;k++) s += wr[k]*w_proj[k*64+o];
  W_op[idx] = s;
}

__global__ __launch_bounds__(256) void k_cvec(
    const float* __restrict__ b_op, const float* __restrict__ w_in2,
    float* __restrict__ cvec){
  int j = blockIdx.x*256 + threadIdx.x;
  float s = 0.f;
  for (int o=0;o<64;o++) s += b_op[o]*w_in2[(size_t)o*4096 + j];
  cvec[j] = s;
}

// dst[p*inner+i] = pack_f16(src[(2p)*inner+i], src[(2p+1)*inner+i])
__global__ __launch_bounds__(256) void k_pack(
    const float* __restrict__ src, uint32* __restrict__ dst,
    int inner, int total){
  int idx = blockIdx.x*256 + threadIdx.x;
  if (idx >= total) return;
  int p = idx / inner, i = idx - p*inner;
  dst[idx] = pk2(src[(size_t)(2*p)*inner + i], src[(size_t)(2*p+1)*inner + i]);
}

// w_x [2048][192] f32 -> wxp4: word(k2,n) at ((k2>>2)*192 + n)*4 + (k2&3)
__global__ __launch_bounds__(256) void k_pack_wx(
    const float* __restrict__ w_x, uint32* __restrict__ dst){
  int idx = blockIdx.x*256 + threadIdx.x;   // [0, 196608)
  int q = idx & 3;
  int t = idx >> 2;                         // [0, 49152)
  int n = t % 192;
  int g = t / 192;                          // [0, 256)
  int k2 = g*4 + q;
  dst[idx] = pk2(w_x[(size_t)(2*k2)*192 + n], w_x[(size_t)(2*k2+1)*192 + n]);
}

// W_op [2048][64] f32 -> wopp4: word(k2,o) at ((k2>>2)*64 + o)*4 + (k2&3)
__global__ __launch_bounds__(256) void k_pack_wop(
    const float* __restrict__ W_op, uint32* __restrict__ dst){
  int idx = blockIdx.x*256 + threadIdx.x;   // [0, 65536)
  int q = idx & 3;
  int t = idx >> 2;
  int o = t & 63;
  int g = t >> 6;                           // [0, 256)
  int k2 = g*4 + q;
  dst[idx] = pk2(W_op[(size_t)(2*k2)*64 + o], W_op[(size_t)(2*k2+1)*64 + o]);
}

// w_dt [64][2048] f32 -> wdtp4: uint4 groups over (p-pair, c-pair)
__global__ __launch_bounds__(256) void k_pack_wdt(
    const float* __restrict__ w_dt, uint32* __restrict__ dst){
  int idx = blockIdx.x*256 + threadIdx.x;   // [0, 65536)
  int e = idx & 3;
  int t = idx >> 2;
  int c2 = t & 1023;
  int jp = t >> 10;                         // [0,16)
  int p = jp*2 + (e>>1);
  int c = c2*2 + (e&1);
  dst[idx] = pk2(w_dt[(size_t)(2*p)*2048 + c], w_dt[(size_t)(2*p+1)*2048 + c]);
}

// ---------------- persistent step kernel (no inter-block sync) ----------------

__global__ __launch_bounds__(1024,4) void k_steps(
    const float* __restrict__ ctx_xz, const float* __restrict__ cvec,
    const uint32* __restrict__ h_in2p, const float* __restrict__ conv_w,
    const float* __restrict__ conv_b,  const uint32* __restrict__ wxp4,
    const uint32* __restrict__ wdtp4,  const float* __restrict__ b_dt,
    const float* __restrict__ D_skip,  const uint32* __restrict__ wopp4,
    const float* __restrict__ b_op,    const float* __restrict__ initial,
    float* __restrict__ dout)
{
  const int tid  = threadIdx.x;
  const int wid  = tid >> 6;
  const int lane = tid & 63;
  const int r0   = blockIdx.x * 2;    // this block's 2 batch rows

  __shared__ __align__(16) uint32 xbufH[2][1024];   // x (then y) f16 pairs [r][k2]
  __shared__ float  zbuf[2][2048];    // silu(z), fp32
  __shared__ float  pxd[4][388];      // xdbc k-slice partials (padded)
  __shared__ float  ppd[16][130];     // pred k-slice partials (pad 130)
  __shared__ uint4  wxpin[6144];      // 96 KB: pinned head of wxp4 (j<8 per ks)
  __shared__ uint32 predH2W[16][64];  // per-wave pred f16-pair words
  __shared__ uint4  xdh2qW[16][16];   // per-wave xdbc[:, :64] f16-pair groups

  // ---- pin wxp4 head into LDS (once) ----
  {
    const uint4* src = (const uint4*)wxp4;
    for (int i = tid; i < 6144; i += 1024){
      int ks = i / 1536;
      wxpin[i] = src[i + ks*10752];
    }
  }

  // ---- step-invariant per-thread preloads ----
  const int cb = tid*4;               // P1: cols cb..cb+3 of xz (0..4095)
  const bool isx = (cb < 2048);
  float4 cw4, cb4;
  if (isx){
    cw4 = make_float4(conv_w[(cb+0)*4+3], conv_w[(cb+1)*4+3],
                      conv_w[(cb+2)*4+3], conv_w[(cb+3)*4+3]);
    cb4 = *(const float4*)&conv_b[cb];
  }
  const float4 cv4   = *(const float4*)&cvec[cb];
  const float4 ctxr0 = *(const float4*)&ctx_xz[(size_t)(r0+0)*4096 + cb];
  const float4 ctxr1 = *(const float4*)&ctx_xz[(size_t)(r0+1)*4096 + cb];
  const int c2t = tid*2;              // P3: cols c2t, c2t+1 of d_inner
  const float2 bdt2 = *(const float2*)&b_dt[c2t];
  const float2 dsk2 = *(const float2*)&D_skip[c2t];
  const int n2  = tid % 192;          // P2: n x 512-K slice (768 threads)
  const int ks2 = tid / 192;
  const int o4  = tid & 63;           // P4: o x 128-K slice (all threads)
  const int kb2 = (tid >> 6) * 64;    //     k2 base
  const float2 bop2 = *(const float2*)&b_op[lane & ~1];  // b_op[2q], b_op[2q+1]

  // init pred = initial, per-wave: word w = pk2(init[r0+b][2q], init[r0+b][2q+1])
  {
    int q = lane>>1, b = lane&1;
    float va = initial[(size_t)(r0+b)*64 + 2*q];
    float vc = initial[(size_t)(r0+b)*64 + 2*q + 1];
    predH2W[wid][lane] = pk2(va, vc);
  }
  __syncthreads();                    // covers wxpin (cross-wave) + init

  for (int t=0; t<96; t++){
    // ---- P1: xz = ctx (+cvec) + pred @ w_in2 (dot2); x=silu(conv), zs=silu ----
    const float tf = (t > 0) ? 1.f : 0.f;
    float a0[4], a1[4];
#pragma unroll
    for (int i=0;i<4;i++){
      float c = (&cv4.x)[i];
      a0[i] = (&ctxr0.x)[i] + tf*c;
      a1[i] = (&ctxr1.x)[i] + tf*c;
    }
    {
      const uint32* wp = h_in2p + cb;   // [o2][j]
      const uint2* pdW = (const uint2*)&predH2W[wid][0];
#pragma unroll 8
      for (int o2=0;o2<32;o2++){
        uint4 w  = *(const uint4*)&wp[(size_t)o2*4096];
        uint2 pd = pdW[o2];
        a0[0]=dot2(w.x,pd.x,a0[0]); a0[1]=dot2(w.y,pd.x,a0[1]);
        a0[2]=dot2(w.z,pd.x,a0[2]); a0[3]=dot2(w.w,pd.x,a0[3]);
        a1[0]=dot2(w.x,pd.y,a1[0]); a1[1]=dot2(w.y,pd.y,a1[1]);
        a1[2]=dot2(w.z,pd.y,a1[2]); a1[3]=dot2(w.w,pd.y,a1[3]);
      }
    }
    if (isx){
      float x0[4], x1[4];
#pragma unroll
      for (int i=0;i<4;i++){
        float v0 = a0[i]*(&cw4.x)[i] + (&cb4.x)[i];
        float v1 = a1[i]*(&cw4.x)[i] + (&cb4.x)[i];
        x0[i] = v0*sigf(v0);
        x1[i] = v1*sigf(v1);
      }
      const int p = cb >> 1;
      *(uint2*)&xbufH[0][p] = make_uint2(pk2(x0[0], x0[1]), pk2(x0[2], x0[3]));
      *(uint2*)&xbufH[1][p] = make_uint2(pk2(x1[0], x1[1]), pk2(x1[2], x1[3]));
    } else {
      float4 z0, z1;
#pragma unroll
      for (int i=0;i<4;i++){
        (&z0.x)[i] = a0[i]*sigf(a0[i]);
        (&z1.x)[i] = a1[i]*sigf(a1[i]);
      }
      *(float4*)&zbuf[0][cb-2048] = z0;
      *(float4*)&zbuf[1][cb-2048] = z1;
    }
    __syncthreads();                    // B1: xbufH/zbuf ready

    // ---- P2: xdbc partials (dot2), 768 threads: (n, 256-k2 slice), uint4 ----
    if (tid < 768){
      const uint4* wpin = &wxpin[ks2*1536 + n2];
      const uint4* wp4  = (const uint4*)wxp4 + (size_t)ks2*12288 + n2;
      const uint4* xb0  = (const uint4*)&xbufH[0][ks2*256];
      const uint4* xb1  = (const uint4*)&xbufH[1][ks2*256];
      float f0 = 0.f, f1 = 0.f;
#pragma unroll
      for (int j=0;j<8;j++){
        uint4 w  = wpin[j*192];
        uint4 x0 = xb0[j];
        uint4 x1 = xb1[j];
        f0 = dot2(w.x, x0.x, f0); f1 = dot2(w.x, x1.x, f1);
        f0 = dot2(w.y, x0.y, f0); f1 = dot2(w.y, x1.y, f1);
        f0 = dot2(w.z, x0.z, f0); f1 = dot2(w.z, x1.z, f1);
        f0 = dot2(w.w, x0.w, f0); f1 = dot2(w.w, x1.w, f1);
      }
#pragma unroll 8
      for (int j=8;j<64;j++){
        uint4 w  = wp4[(size_t)j*192];
        uint4 x0 = xb0[j];
        uint4 x1 = xb1[j];
        f0 = dot2(w.x, x0.x, f0); f1 = dot2(w.x, x1.x, f1);
        f0 = dot2(w.y, x0.y, f0); f1 = dot2(w.y, x1.y, f1);
        f0 = dot2(w.z, x0.z, f0); f1 = dot2(w.z, x1.z, f1);
        f0 = dot2(w.w, x0.w, f0); f1 = dot2(w.w, x1.w, f1);
      }
      *(float2*)&pxd[ks2][n2*2] = make_float2(f0, f1);
    }
    __syncthreads();                    // B2: pxd ready

    // ---- per-wave: bc butterfly (all waves, bit-identical) + xdh2q pack ----
    float bc0, bc1;
    {
      int ib0 = (64+lane)*2, ic0 = (128+lane)*2;
      float bv0 = pxd[0][ib0]+pxd[1][ib0]+pxd[2][ib0]+pxd[3][ib0];
      float cv0 = pxd[0][ic0]+pxd[1][ic0]+pxd[2][ic0]+pxd[3][ic0];
      float p0 = bv0*cv0;
      int ib1 = ib0+1, ic1 = ic0+1;
      float bv1 = pxd[0][ib1]+pxd[1][ib1]+pxd[2][ib1]+pxd[3][ib1];
      float cv1 = pxd[0][ic1]+pxd[1][ic1]+pxd[2][ic1]+pxd[3][ic1];
      float p1 = bv1*cv1;
#pragma unroll
      for (int sh=1; sh<64; sh<<=1){
        p0 += __shfl_xor(p0, sh, 64);
        p1 += __shfl_xor(p1, sh, 64);
      }
      bc0 = p0; bc1 = p1;
      if (lane < 32){
        int o2 = lane;
        int i00 = (2*o2)*2, i10 = (2*o2+1)*2;
        float v00 = pxd[0][i00  ]+pxd[1][i00  ]+pxd[2][i00  ]+pxd[3][i00  ];
        float v01 = pxd[0][i00+1]+pxd[1][i00+1]+pxd[2][i00+1]+pxd[3][i00+1];
        float v10 = pxd[0][i10  ]+pxd[1][i10  ]+pxd[2][i10  ]+pxd[3][i10  ];
        float v11 = pxd[0][i10+1]+pxd[1][i10+1]+pxd[2][i10+1]+pxd[3][i10+1];
        ((uint2*)&xdh2qW[wid][0])[o2] = make_uint2(pk2(v00, v10), pk2(v01, v11));
      }
      ldsfence();                       // own-wave xdh2qW visible
    }

    // ---- dt GEMM (dot2, K=64, uint4) + y (in-place y -> xbufH) ----
    float d00=0.f, d01=0.f, d10=0.f, d11=0.f;
    {
      const uint4* wd4 = (const uint4*)wdtp4 + tid;
#pragma unroll 8
      for (int jp=0;jp<16;jp++){
        uint4 w  = wd4[(size_t)jp*1024];
        uint4 xd = xdh2qW[wid][jp];
        d00 = dot2(w.x, xd.x, d00);
        d01 = dot2(w.y, xd.x, d01);
        d10 = dot2(w.x, xd.y, d10);
        d11 = dot2(w.y, xd.y, d11);
        d00 = dot2(w.z, xd.z, d00);
        d01 = dot2(w.w, xd.z, d01);
        d10 = dot2(w.z, xd.w, d10);
        d11 = dot2(w.w, xd.w, d11);
      }
    }
    {
      HU xh0, xh1; xh0.u = xbufH[0][tid]; xh1.u = xbufH[1][tid];
      float2 zr0 = *(const float2*)&zbuf[0][c2t];
      float2 zr1 = *(const float2*)&zbuf[1][c2t];
      float v00 = d00 + bdt2.x, v01 = d01 + bdt2.y;
      float v10 = d10 + bdt2.x, v11 = d11 + bdt2.y;
      float s00 = (v00 > 15.f) ? v00 : __logf(1.f + __expf(v00));
      float s01 = (v01 > 15.f) ? v01 : __logf(1.f + __expf(v01));
      float s10 = (v10 > 15.f) ? v10 : __logf(1.f + __expf(v10));
      float s11 = (v11 > 15.f) ? v11 : __logf(1.f + __expf(v11));
      float y00 = (s00*bc0 + dsk2.x) * (float)xh0.h.x * zr0.x;
      float y01 = (s01*bc0 + dsk2.y) * (float)xh0.h.y * zr0.y;
      float y10 = (s10*bc1 + dsk2.x) * (float)xh1.h.x * zr1.x;
      float y11 = (s11*bc1 + dsk2.y) * (float)xh1.h.y * zr1.y;
      // same-thread read-then-write of xbufH[.][tid]: no cross-thread hazard
      xbufH[0][tid] = pk2(y00, y01);
      xbufH[1][tid] = pk2(y10, y11);
    }
    __syncthreads();                    // B4: y ready for P4

    // ---- P4: pred partials (dot2), all threads: (o, 64-k2 slice), uint4 ----
    {
      const uint4* wo4 = (const uint4*)wopp4 + (size_t)(tid>>6)*1024 + o4;
      const uint4* yb0 = (const uint4*)&xbufH[0][kb2];
      const uint4* yb1 = (const uint4*)&xbufH[1][kb2];
      float p0 = 0.f, p1 = 0.f;
#pragma unroll 8
      for (int j=0;j<16;j++){
        uint4 w  = wo4[(size_t)j*64];
        uint4 y0 = yb0[j];
        uint4 y1 = yb1[j];
        p0 = dot2(w.x, y0.x, p0); p1 = dot2(w.x, y1.x, p1);
        p0 = dot2(w.y, y0.y, p0); p1 = dot2(w.y, y1.y, p1);
        p0 = dot2(w.z, y0.z, p0); p1 = dot2(w.z, y1.z, p1);
        p0 = dot2(w.w, y0.w, p0); p1 = dot2(w.w, y1.w, p1);
      }
      *(float2*)&ppd[tid>>6][o4*2] = make_float2(p0, p1);
    }
    __syncthreads();                    // B5: ppd ready

    // ---- per-wave pred reduce (all waves, bit-identical) + dout (wave 0) ----
    {
      int q = lane>>1, b = lane&1;
      int a = 4*q + b;                  // word lane = pk2(v[a], v[a+2])
      float va = 0.f, vc = 0.f;
#pragma unroll
      for (int ks=0; ks<16; ks++){
        va += ppd[ks][a];
        vc += ppd[ks][a+2];
      }
      if (wid == 0){
        float* dp = &dout[((size_t)(r0+b)*96 + t)*64 + 2*q];
        *(float2*)dp = make_float2(va + bop2.x, vc + bop2.y);
      }
      predH2W[wid][lane] = pk2(va, vc);
      ldsfence();                       // own-wave predH2W visible for next P1
    }
    // no barrier: next P1 reads only predH2W[wid] (own wave) and writes
    // xbufH/zbuf, whose last cross-wave readers ran before B5.
  }
}

// ---------------- launch ----------------

extern "C" void kernel_launch(void* const* d_in, const int* in_sizes, int n_in,
                              void* d_out, int out_size, void* d_ws, size_t ws_size,
                              hipStream_t stream)
{
  const float* context = (const float*)d_in[0];
  const float* initial = (const float*)d_in[1];
  const float* w_in    = (const float*)d_in[2];
  const float* b_in    = (const float*)d_in[3];
  const float* conv_w  = (const float*)d_in[4];
  const float* conv_b  = (const float*)d_in[5];
  const float* w_x     = (const float*)d_in[6];
  const float* w_dt    = (const float*)d_in[7];
  const float* b_dt    = (const float*)d_in[8];
  // d_in[9] = A_log (unused: L=1, h0=0)
  const float* D_skip  = (const float*)d_in[10];
  const float* w_out   = (const float*)d_in[11];
  const float* b_out   = (const float*)d_in[12];
  const float* w_proj  = (const float*)d_in[13];
  const float* b_proj  = (const float*)d_in[14];

  float* ws = (float*)d_ws;
  float*  ctx_xz = ws;                       // 2,097,152 f
  float*  cvec   = ctx_xz + 2097152;         // 4,096 f
  float*  W_op   = cvec + 4096;              // 131,072 f
  float*  b_op   = W_op + 131072;            // 128 f
  uint32* h_in2p = (uint32*)(b_op + 128);    // 131,072 u  [32][4096]
  uint32* wxp4   = h_in2p + 131072;          // 196,608 u  uint4-grouped
  uint32* wdtp4  = wxp4 + 196608;            // 65,536 u   uint4-grouped
  uint32* wopp4  = wdtp4 + 65536;            // 65,536 u   uint4-grouped
  float*  dout   = (float*)d_out;

  const float* w_in2 = w_in + (size_t)1024*4096;

  k_wop     <<<dim3(513),   256, 0, stream>>>(w_out, w_proj, b_out, b_proj, W_op, b_op);
  k_cvec    <<<dim3(16),    256, 0, stream>>>(b_op, w_in2, cvec);
  k_ctx     <<<dim3(16,32), 256, 0, stream>>>(context, w_in, b_in, ctx_xz);
  k_pack    <<<dim3(512),   256, 0, stream>>>(w_in2, h_in2p, 4096, 131072);
  k_pack_wx <<<dim3(768),   256, 0, stream>>>(w_x,  wxp4);
  k_pack_wdt<<<dim3(256),   256, 0, stream>>>(w_dt, wdtp4);
  k_pack_wop<<<dim3(256),   256, 0, stream>>>(W_op, wopp4);

  k_steps<<<dim3(256), 1024, 0, stream>>>(ctx_xz, cvec, h_in2p, conv_w, conv_b,
                                          wxp4, wdtp4, b_dt, D_skip, wopp4, b_op,
                                          initial, dout);
}

// Round 12
// 2008.991 us; speedup vs baseline: 1.0660x; 1.0660x over previous
//
#include <hip/hip_runtime.h>
#include <math.h>

// B=512, D_MODEL=1024, D_INNER=2048, DT_RANK=64, D_STATE=64, NBC=192,
// C_OUT=64, PRED_LEN=96.
// R21 == R16 exact revert (best verified: json 2042.8us; steady 1977-2003).
// R16 = R14 + LDS weight pin extended to 120KB (wxpin j<10 per ks).
// Session ledger: byte-reduction at the calibrated ~135-139 GB/s/CU marginal
// rate was the only working lever (R14: -96KB/step matched prediction);
// R16/R19 byte-cuts neutral (latency-bound with spare port capacity);
// all six overlap/barrier mechanisms regressed (R12 remat, R13 spill,
// R15 thrash 4.2GB, R17 thrash 2.7x, R18 thrash 1.4x, R20 LDS-conflict 32x).
// Structural ceiling: ~12.4us/step weight stream + ~8us serial phase
// structure the HIP compiler won't overlap.

typedef __fp16 half2_t __attribute__((ext_vector_type(2)));
typedef unsigned int uint32;
union HU { uint32 u; half2_t h; };

__device__ __forceinline__ float sigf(float v){
  return __builtin_amdgcn_rcpf(1.f + __expf(-v));
}
__device__ __forceinline__ uint32 pk2(float a, float b){
  HU x; x.h = __builtin_amdgcn_cvt_pkrtz(a, b); return x.u;
}
__device__ __forceinline__ float dot2(uint32 a, uint32 b, float c){
  HU ua, ub; ua.u = a; ub.u = b;
  return __builtin_amdgcn_fdot2(ua.h, ub.h, c, false);
}

// ---------------- setup kernels ----------------

__global__ __launch_bounds__(256) void k_ctx(
    const float* __restrict__ ctxin, const float* __restrict__ w_in,
    const float* __restrict__ b_in, float* __restrict__ ctx_xz){
  int tid = threadIdx.x;
  int j = blockIdx.x*256 + tid;
  int b0 = blockIdx.y*16;
  const float* cp = ctxin + (size_t)b0*1024;
  float acc[16];
#pragma unroll
  for (int r=0;r<16;r++) acc[r]=0.f;
  for (int k=0;k<1024;k+=4){
    float w0 = w_in[(size_t)(k+0)*4096 + j];
    float w1 = w_in[(size_t)(k+1)*4096 + j];
    float w2 = w_in[(size_t)(k+2)*4096 + j];
    float w3 = w_in[(size_t)(k+3)*4096 + j];
#pragma unroll
    for (int r=0;r<16;r++){
      acc[r] += cp[r*1024+k]*w0 + cp[r*1024+k+1]*w1
              + cp[r*1024+k+2]*w2 + cp[r*1024+k+3]*w3;
    }
  }
  float bj = b_in[j];
#pragma unroll
  for (int r=0;r<16;r++) ctx_xz[(size_t)(b0+r)*4096 + j] = acc[r] + bj;
}

// W_op[c][o] = sum_k w_out[c][k]*w_proj[k][o]; b_op = b_out@w_proj + b_proj
__global__ __launch_bounds__(256) void k_wop(
    const float* __restrict__ w_out, const float* __restrict__ w_proj,
    const float* __restrict__ b_out, const float* __restrict__ b_proj,
    float* __restrict__ W_op, float* __restrict__ b_op){
  int g = blockIdx.x, tid = threadIdx.x;
  if (g == 512){
    if (tid < 64){
      float s = b_proj[tid];
      for (int k=0;k<1024;k++) s += b_out[k]*w_proj[k*64+tid];
      b_op[tid] = s;
    }
    return;
  }
  int idx = g*256 + tid;
  int c = idx>>6, o = idx&63;
  float s = 0.f;
  const float* wr = w_out + (size_t)c*1024;
  for (int k=0;k<1024;k++) s += wr[k]*w_proj[k*64+o];
  W_op[idx] = s;
}

__global__ __launch_bounds__(256) void k_cvec(
    const float* __restrict__ b_op, const float* __restrict__ w_in2,
    float* __restrict__ cvec){
  int j = blockIdx.x*256 + threadIdx.x;
  float s = 0.f;
  for (int o=0;o<64;o++) s += b_op[o]*w_in2[(size_t)o*4096 + j];
  cvec[j] = s;
}

// dst[p*inner+i] = pack_f16(src[(2p)*inner+i], src[(2p+1)*inner+i])
__global__ __launch_bounds__(256) void k_pack(
    const float* __restrict__ src, uint32* __restrict__ dst,
    int inner, int total){
  int idx = blockIdx.x*256 + threadIdx.x;
  if (idx >= total) return;
  int p = idx / inner, i = idx - p*inner;
  dst[idx] = pk2(src[(size_t)(2*p)*inner + i], src[(size_t)(2*p+1)*inner + i]);
}

// w_x [2048][192] f32 -> wxp4: word(k2,n) at ((k2>>2)*192 + n)*4 + (k2&3)
__global__ __launch_bounds__(256) void k_pack_wx(
    const float* __restrict__ w_x, uint32* __restrict__ dst){
  int idx = blockIdx.x*256 + threadIdx.x;   // [0, 196608)
  int q = idx & 3;
  int t = idx >> 2;                         // [0, 49152)
  int n = t % 192;
  int g = t / 192;                          // [0, 256)
  int k2 = g*4 + q;
  dst[idx] = pk2(w_x[(size_t)(2*k2)*192 + n], w_x[(size_t)(2*k2+1)*192 + n]);
}

// W_op [2048][64] f32 -> wopp4: word(k2,o) at ((k2>>2)*64 + o)*4 + (k2&3)
__global__ __launch_bounds__(256) void k_pack_wop(
    const float* __restrict__ W_op, uint32* __restrict__ dst){
  int idx = blockIdx.x*256 + threadIdx.x;   // [0, 65536)
  int q = idx & 3;
  int t = idx >> 2;
  int o = t & 63;
  int g = t >> 6;                           // [0, 256)
  int k2 = g*4 + q;
  dst[idx] = pk2(W_op[(size_t)(2*k2)*64 + o], W_op[(size_t)(2*k2+1)*64 + o]);
}

// w_dt [64][2048] f32 -> wdtp4: uint4 groups over (p-pair, c-pair)
__global__ __launch_bounds__(256) void k_pack_wdt(
    const float* __restrict__ w_dt, uint32* __restrict__ dst){
  int idx = blockIdx.x*256 + threadIdx.x;   // [0, 65536)
  int e = idx & 3;
  int t = idx >> 2;
  int c2 = t & 1023;
  int jp = t >> 10;                         // [0,16)
  int p = jp*2 + (e>>1);
  int c = c2*2 + (e&1);
  dst[idx] = pk2(w_dt[(size_t)(2*p)*2048 + c], w_dt[(size_t)(2*p+1)*2048 + c]);
}

// ---------------- persistent step kernel (no inter-block sync) ----------------

__global__ __launch_bounds__(1024,4) void k_steps(
    const float* __restrict__ ctx_xz, const float* __restrict__ cvec,
    const uint32* __restrict__ h_in2p, const float* __restrict__ conv_w,
    const float* __restrict__ conv_b,  const uint32* __restrict__ wxp4,
    const uint32* __restrict__ wdtp4,  const float* __restrict__ b_dt,
    const float* __restrict__ D_skip,  const uint32* __restrict__ wopp4,
    const float* __restrict__ b_op,    const float* __restrict__ initial,
    float* __restrict__ dout)
{
  const int tid = threadIdx.x;
  const int r0  = blockIdx.x * 2;     // this block's 2 batch rows

  __shared__ uint2  predH2[32];       // pred f16 pairs: [o2] = (row0pair, row1pair)
  __shared__ __align__(16) uint32 xbufH[2][1024];   // x (then y) f16 pairs [r][k2]
  __shared__ float  zbuf[2][2048];    // silu(z), fp32
  __shared__ uint4  xdh2q[16];        // xdbc[:, :64] f16 pairs, uint4 groups
  __shared__ float  bcL[2];
  __shared__ float  pxd[4][388];      // xdbc k-slice partials (padded)
  __shared__ float  ppd[16][130];     // pred k-slice partials (pad 130)
  __shared__ uint4  wxpin[7680];      // 120 KB: pinned head of wxp4 (j<10 per ks)

  // ---- pin wxp4 head into LDS (once) ----
  // wxpin[ks*1920 + j*192 + n] = wxp4_uint4[ks*12288 + j*192 + n], j<10
  {
    const uint4* src = (const uint4*)wxp4;
    for (int i = tid; i < 7680; i += 1024){
      int ks = i / 1920;
      wxpin[i] = src[i + ks*10368];
    }
  }

  // ---- step-invariant per-thread preloads ----
  const int cb = tid*4;               // P1: cols cb..cb+3 of xz (0..4095)
  const bool isx = (cb < 2048);
  float4 cw4, cb4;
  if (isx){
    cw4 = make_float4(conv_w[(cb+0)*4+3], conv_w[(cb+1)*4+3],
                      conv_w[(cb+2)*4+3], conv_w[(cb+3)*4+3]);
    cb4 = *(const float4*)&conv_b[cb];
  }
  const float4 cv4   = *(const float4*)&cvec[cb];
  const float4 ctxr0 = *(const float4*)&ctx_xz[(size_t)(r0+0)*4096 + cb];
  const float4 ctxr1 = *(const float4*)&ctx_xz[(size_t)(r0+1)*4096 + cb];
  const int c2t = tid*2;              // P3: cols c2t, c2t+1 of d_inner
  const float2 bdt2 = *(const float2*)&b_dt[c2t];
  const float2 dsk2 = *(const float2*)&D_skip[c2t];
  const int n2  = tid % 192;          // P2: n x 512-K slice (768 threads)
  const int ks2 = tid / 192;
  const int o4  = tid & 63;           // P4: o x 128-K slice (all threads)
  const int kb2 = (tid >> 6) * 64;    //     k2 base
  const float bopv = b_op[(tid>>1) & 63];

  // init pred = initial, packed to f16 pairs
  if (tid < 128){
    float v = initial[(size_t)(r0 + (tid&1))*64 + (tid>>1)];
    float vp = __shfl_down(v, 2, 64);
    if ((tid & 2) == 0)
      ((uint32*)predH2)[(tid>>2)*2 + (tid&1)] = pk2(v, vp);
  }
  __syncthreads();

  for (int t=0; t<96; t++){
    // ---- P1: xz = ctx (+cvec) + pred @ w_in2 (dot2); x=silu(conv), zs=silu ----
    const float tf = (t > 0) ? 1.f : 0.f;
    float a0[4], a1[4];
#pragma unroll
    for (int i=0;i<4;i++){
      float c = (&cv4.x)[i];
      a0[i] = (&ctxr0.x)[i] + tf*c;
      a1[i] = (&ctxr1.x)[i] + tf*c;
    }
    {
      const uint32* wp = h_in2p + cb;   // [o2][j]
#pragma unroll 8
      for (int o2=0;o2<32;o2++){
        uint4 w  = *(const uint4*)&wp[(size_t)o2*4096];
        uint2 pd = *((const uint2*)predH2 + o2);
        a0[0]=dot2(w.x,pd.x,a0[0]); a0[1]=dot2(w.y,pd.x,a0[1]);
        a0[2]=dot2(w.z,pd.x,a0[2]); a0[3]=dot2(w.w,pd.x,a0[3]);
        a1[0]=dot2(w.x,pd.y,a1[0]); a1[1]=dot2(w.y,pd.y,a1[1]);
        a1[2]=dot2(w.z,pd.y,a1[2]); a1[3]=dot2(w.w,pd.y,a1[3]);
      }
    }
    if (isx){
      float x0[4], x1[4];
#pragma unroll
      for (int i=0;i<4;i++){
        float v0 = a0[i]*(&cw4.x)[i] + (&cb4.x)[i];
        float v1 = a1[i]*(&cw4.x)[i] + (&cb4.x)[i];
        x0[i] = v0*sigf(v0);
        x1[i] = v1*sigf(v1);
      }
      const int p = cb >> 1;
      *(uint2*)&xbufH[0][p] = make_uint2(pk2(x0[0], x0[1]), pk2(x0[2], x0[3]));
      *(uint2*)&xbufH[1][p] = make_uint2(pk2(x1[0], x1[1]), pk2(x1[2], x1[3]));
    } else {
      float4 z0, z1;
#pragma unroll
      for (int i=0;i<4;i++){
        (&z0.x)[i] = a0[i]*sigf(a0[i]);
        (&z1.x)[i] = a1[i]*sigf(a1[i]);
      }
      *(float4*)&zbuf[0][cb-2048] = z0;
      *(float4*)&zbuf[1][cb-2048] = z1;
    }
    __syncthreads();

    // ---- P2: xdbc partials (dot2), 768 threads: (n, 256-k2 slice), uint4 ----
    // j<10 weights from pinned LDS (wxpin), j>=10 streamed from L2.
    if (tid < 768){
      const uint4* wpin = &wxpin[ks2*1920 + n2];
      const uint4* wp4  = (const uint4*)wxp4 + (size_t)ks2*12288 + n2;
      const uint4* xb0  = (const uint4*)&xbufH[0][ks2*256];
      const uint4* xb1  = (const uint4*)&xbufH[1][ks2*256];
      float f0 = 0.f, f1 = 0.f;
#pragma unroll
      for (int j=0;j<10;j++){
        uint4 w  = wpin[j*192];
        uint4 x0 = xb0[j];
        uint4 x1 = xb1[j];
        f0 = dot2(w.x, x0.x, f0); f1 = dot2(w.x, x1.x, f1);
        f0 = dot2(w.y, x0.y, f0); f1 = dot2(w.y, x1.y, f1);
        f0 = dot2(w.z, x0.z, f0); f1 = dot2(w.z, x1.z, f1);
        f0 = dot2(w.w, x0.w, f0); f1 = dot2(w.w, x1.w, f1);
      }
#pragma unroll 6
      for (int j=10;j<64;j++){
        uint4 w  = wp4[(size_t)j*192];
        uint4 x0 = xb0[j];
        uint4 x1 = xb1[j];
        f0 = dot2(w.x, x0.x, f0); f1 = dot2(w.x, x1.x, f1);
        f0 = dot2(w.y, x0.y, f0); f1 = dot2(w.y, x1.y, f1);
        f0 = dot2(w.z, x0.z, f0); f1 = dot2(w.z, x1.z, f1);
        f0 = dot2(w.w, x0.w, f0); f1 = dot2(w.w, x1.w, f1);
      }
      *(float2*)&pxd[ks2][n2*2] = make_float2(f0, f1);
    }
    __syncthreads();

    // ---- merged: bc (128 threads, 4-way reduce inline) + pack (32 threads) ----
    if (tid < 128){
      int r = tid >> 6, nl = tid & 63;
      int ib = (64+nl)*2 + r, ic = (128+nl)*2 + r;
      float bv = pxd[0][ib] + pxd[1][ib] + pxd[2][ib] + pxd[3][ib];
      float cv = pxd[0][ic] + pxd[1][ic] + pxd[2][ic] + pxd[3][ic];
      float p = bv * cv;
#pragma unroll
      for (int sh=1; sh<64; sh<<=1) p += __shfl_xor(p, sh, 64);
      if (nl == 0) bcL[r] = p;
    } else if (tid < 160){
      int o2 = tid - 128;
      int i00 = (2*o2)*2, i10 = (2*o2+1)*2;
      float v00 = pxd[0][i00  ] + pxd[1][i00  ] + pxd[2][i00  ] + pxd[3][i00  ];
      float v01 = pxd[0][i00+1] + pxd[1][i00+1] + pxd[2][i00+1] + pxd[3][i00+1];
      float v10 = pxd[0][i10  ] + pxd[1][i10  ] + pxd[2][i10  ] + pxd[3][i10  ];
      float v11 = pxd[0][i10+1] + pxd[1][i10+1] + pxd[2][i10+1] + pxd[3][i10+1];
      ((uint32*)xdh2q)[o2*2+0] = pk2(v00, v10);
      ((uint32*)xdh2q)[o2*2+1] = pk2(v01, v11);
    }
    __syncthreads();

    // ---- dt GEMM (dot2, K=64, uint4) + y (in-place y -> xbufH) ----
    float d00=0.f, d01=0.f, d10=0.f, d11=0.f;
    {
      const uint4* wd4 = (const uint4*)wdtp4 + tid;
#pragma unroll 8
      for (int jp=0;jp<16;jp++){
        uint4 w  = wd4[(size_t)jp*1024];
        uint4 xd = xdh2q[jp];
        d00 = dot2(w.x, xd.x, d00);
        d01 = dot2(w.y, xd.x, d01);
        d10 = dot2(w.x, xd.y, d10);
        d11 = dot2(w.y, xd.y, d11);
        d00 = dot2(w.z, xd.z, d00);
        d01 = dot2(w.w, xd.z, d01);
        d10 = dot2(w.z, xd.w, d10);
        d11 = dot2(w.w, xd.w, d11);
      }
    }
    {
      float bc0 = bcL[0], bc1 = bcL[1];
      HU xh0, xh1; xh0.u = xbufH[0][tid]; xh1.u = xbufH[1][tid];
      float2 zr0 = *(const float2*)&zbuf[0][c2t];
      float2 zr1 = *(const float2*)&zbuf[1][c2t];
      float v00 = d00 + bdt2.x, v01 = d01 + bdt2.y;
      float v10 = d10 + bdt2.x, v11 = d11 + bdt2.y;
      float s00 = (v00 > 15.f) ? v00 : __logf(1.f + __expf(v00));
      float s01 = (v01 > 15.f) ? v01 : __logf(1.f + __expf(v01));
      float s10 = (v10 > 15.f) ? v10 : __logf(1.f + __expf(v10));
      float s11 = (v11 > 15.f) ? v11 : __logf(1.f + __expf(v11));
      float y00 = (s00*bc0 + dsk2.x) * (float)xh0.h.x * zr0.x;
      float y01 = (s01*bc0 + dsk2.y) * (float)xh0.h.y * zr0.y;
      float y10 = (s10*bc1 + dsk2.x) * (float)xh1.h.x * zr1.x;
      float y11 = (s11*bc1 + dsk2.y) * (float)xh1.h.y * zr1.y;
      // same-thread read-then-write of xbufH[.][tid]: no cross-thread hazard
      xbufH[0][tid] = pk2(y00, y01);
      xbufH[1][tid] = pk2(y10, y11);
    }
    __syncthreads();

    // ---- P4: pred partials (dot2), all threads: (o, 64-k2 slice), uint4 ----
    {
      const uint4* wo4 = (const uint4*)wopp4 + (size_t)(tid>>6)*1024 + o4;
      const uint4* yb0 = (const uint4*)&xbufH[0][kb2];
      const uint4* yb1 = (const uint4*)&xbufH[1][kb2];
      float p0 = 0.f, p1 = 0.f;
#pragma unroll 8
      for (int j=0;j<16;j++){
        uint4 w  = wo4[(size_t)j*64];
        uint4 y0 = yb0[j];
        uint4 y1 = yb1[j];
        p0 = dot2(w.x, y0.x, p0); p1 = dot2(w.x, y1.x, p1);
        p0 = dot2(w.y, y0.y, p0); p1 = dot2(w.y, y1.y, p1);
        p0 = dot2(w.z, y0.z, p0); p1 = dot2(w.z, y1.z, p1);
        p0 = dot2(w.w, y0.w, p0); p1 = dot2(w.w, y1.w, p1);
      }
      *(float2*)&ppd[tid>>6][o4*2] = make_float2(p0, p1);
    }
    __syncthreads();

    // ---- reduce pred (128 threads) + dout + pack next predH2 ----
    if (tid < 128){
      float v = 0.f;
#pragma unroll
      for (int ks=0; ks<16; ks++) v += ppd[ks][tid];
      int o = tid >> 1, r = tid & 1;
      dout[((size_t)(r0+r)*96 + t)*64 + o] = v + bopv;
      float vp = __shfl_down(v, 2, 64);
      if ((tid & 2) == 0)
        ((uint32*)predH2)[(tid>>2)*2 + (tid&1)] = pk2(v, vp);
    }
    __syncthreads();
  }
}

// ---------------- launch ----------------

extern "C" void kernel_launch(void* const* d_in, const int* in_sizes, int n_in,
                              void* d_out, int out_size, void* d_ws, size_t ws_size,
                              hipStream_t stream)
{
  const float* context = (const float*)d_in[0];
  const float* initial = (const float*)d_in[1];
  const float* w_in    = (const float*)d_in[2];
  const float* b_in    = (const float*)d_in[3];
  const float* conv_w  = (const float*)d_in[4];
  const float* conv_b  = (const float*)d_in[5];
  const float* w_x     = (const float*)d_in[6];
  const float* w_dt    = (const float*)d_in[7];
  const float* b_dt    = (const float*)d_in[8];
  // d_in[9] = A_log (unused: L=1, h0=0)
  const float* D_skip  = (const float*)d_in[10];
  const float* w_out   = (const float*)d_in[11];
  const float* b_out   = (const float*)d_in[12];
  const float* w_proj  = (const float*)d_in[13];
  const float* b_proj  = (const float*)d_in[14];

  float* ws = (float*)d_ws;
  float*  ctx_xz = ws;                       // 2,097,152 f
  float*  cvec   = ctx_xz + 2097152;         // 4,096 f
  float*  W_op   = cvec + 4096;              // 131,072 f
  float*  b_op   = W_op + 131072;            // 128 f
  uint32* h_in2p = (uint32*)(b_op + 128);    // 131,072 u  [32][4096]
  uint32* wxp4   = h_in2p + 131072;          // 196,608 u  uint4-grouped
  uint32* wdtp4  = wxp4 + 196608;            // 65,536 u   uint4-grouped
  uint32* wopp4  = wdtp4 + 65536;            // 65,536 u   uint4-grouped
  float*  dout   = (float*)d_out;

  const float* w_in2 = w_in + (size_t)1024*4096;

  k_wop     <<<dim3(513),   256, 0, stream>>>(w_out, w_proj, b_out, b_proj, W_op, b_op);
  k_cvec    <<<dim3(16),    256, 0, stream>>>(b_op, w_in2, cvec);
  k_ctx     <<<dim3(16,32), 256, 0, stream>>>(context, w_in, b_in, ctx_xz);
  k_pack    <<<dim3(512),   256, 0, stream>>>(w_in2, h_in2p, 4096, 131072);
  k_pack_wx <<<dim3(768),   256, 0, stream>>>(w_x,  wxp4);
  k_pack_wdt<<<dim3(256),   256, 0, stream>>>(w_dt, wdtp4);
  k_pack_wop<<<dim3(256),   256, 0, stream>>>(W_op, wopp4);

  k_steps<<<dim3(256), 1024, 0, stream>>>(ctx_xz, cvec, h_in2p, conv_w, conv_b,
                                          wxp4, wdtp4, b_dt, D_skip, wopp4, b_op,
                                          initial, dout);
}